// Round 7
// baseline (247.144 us; speedup 1.0000x reference)
//
#include <hip/hip_runtime.h>
#include <hip/hip_bf16.h>

// Problem constants (B=8, T=2048, d_model=512, head_dim=64)
#define TT 2048
#define NB 8
#define DM 512
#define HD 64
static constexpr float SCALE = 0.04419417382415922f; // 512^-0.5

typedef short  s16x8 __attribute__((ext_vector_type(8)));   // 8 bf16 (4 VGPRs)
typedef short  s16x4 __attribute__((ext_vector_type(4)));   // 4 bf16 (2 VGPRs)
typedef float  f32x4 __attribute__((ext_vector_type(4)));

#define MFMA(a, b, c) __builtin_amdgcn_mfma_f32_16x16x32_bf16((a), (b), (c), 0, 0, 0)

// fp32 -> bf16 (RNE)
static __device__ inline unsigned short f2bf(float f) {
    unsigned int u = __float_as_uint(f);
    u += 0x7FFFu + ((u >> 16) & 1u);
    return (unsigned short)(u >> 16);
}

// ----------------------------------------------------------------- qkv ----
// M=32 rows/block, N=192, K=512, grid 512, x staged via LDS. Prep folded in:
// W fragments read as fp32 (L2-resident) + f2bf inline; blocks 0..15 zero
// colsum at start (kernel-boundary ordering protects colsum's atomics).
#define XS 72
__global__ __launch_bounds__(256) void qkv_kernel(
    const float* __restrict__ x,
    const float* __restrict__ Wk, const float* __restrict__ Wq,
    const float* __restrict__ Wv,
    unsigned short* __restrict__ kb, unsigned short* __restrict__ qb,
    unsigned short* __restrict__ vb, float* __restrict__ colsum) {
    __shared__ unsigned short xs[32 * XS];
    const int i0 = blockIdx.x * 32;
    const int t = threadIdx.x;
    if (blockIdx.x < 16) {               // zero colsum: 16,384 floats
        int i = (blockIdx.x * 256 + t) * 4;
        *(float4*)(colsum + i) = make_float4(0.f, 0.f, 0.f, 0.f);
    }
    const int w = t >> 6, lane = t & 63;
    const int m15 = lane & 15, quad = lane >> 4;
    const int srow = t >> 3, c8 = (t & 7) * 8;    // staging: 32 rows x 64 cols
    const float* wrow[3];
    for (int ct = 0; ct < 3; ++ct) {
        int tile16 = w * 3 + ct;
        const float* wsel = (tile16 < 4) ? Wk : (tile16 < 8) ? Wq : Wv;
        wrow[ct] = wsel + (size_t)((tile16 & 3) * 16 + m15) * DM;
    }
    f32x4 acc[2][3];
    for (int mt = 0; mt < 2; ++mt)
        for (int ct = 0; ct < 3; ++ct)
            acc[mt][ct] = (f32x4){0.f, 0.f, 0.f, 0.f};

    for (int kc = 0; kc < DM; kc += 64) {
        __syncthreads();
        {
            const float* gp = x + (size_t)(i0 + srow) * DM + kc + c8;
            float4 f0 = *(const float4*)gp;
            float4 f1 = *(const float4*)(gp + 4);
            s16x8 h;
            h[0] = (short)f2bf(f0.x); h[1] = (short)f2bf(f0.y);
            h[2] = (short)f2bf(f0.z); h[3] = (short)f2bf(f0.w);
            h[4] = (short)f2bf(f1.x); h[5] = (short)f2bf(f1.y);
            h[6] = (short)f2bf(f1.z); h[7] = (short)f2bf(f1.w);
            *(s16x8*)(xs + srow * XS + c8) = h;
        }
        __syncthreads();
        for (int ks = 0; ks < 2; ++ks) {
            s16x8 a[2];
            for (int mt = 0; mt < 2; ++mt)
                a[mt] = *(const s16x8*)(xs + (mt * 16 + m15) * XS + ks * 32 + quad * 8);
            for (int ct = 0; ct < 3; ++ct) {
                const float* wp = wrow[ct] + kc + ks * 32 + quad * 8;
                float4 f0 = *(const float4*)wp;
                float4 f1 = *(const float4*)(wp + 4);
                s16x8 bfr;
                bfr[0] = (short)f2bf(f0.x); bfr[1] = (short)f2bf(f0.y);
                bfr[2] = (short)f2bf(f0.z); bfr[3] = (short)f2bf(f0.w);
                bfr[4] = (short)f2bf(f1.x); bfr[5] = (short)f2bf(f1.y);
                bfr[6] = (short)f2bf(f1.z); bfr[7] = (short)f2bf(f1.w);
                acc[0][ct] = MFMA(a[0], bfr, acc[0][ct]);
                acc[1][ct] = MFMA(a[1], bfr, acc[1][ct]);
            }
        }
    }
    for (int mt = 0; mt < 2; ++mt)
        for (int ct = 0; ct < 3; ++ct) {
            int tile16 = w * 3 + ct;
            unsigned short* outp = (tile16 < 4) ? kb : (tile16 < 8) ? qb : vb;
            int col = (tile16 & 3) * 16 + m15;
            for (int r = 0; r < 4; ++r) {
                int grow = i0 + mt * 16 + quad * 4 + r;
                outp[(size_t)grow * HD + col] = f2bf(acc[mt][ct][r]);
            }
        }
}

// -------------------------------------------------------------- colsum ----
// colsum[b][j] = sum_{i>=j} exp(SCALE * q_i . k_j)  — no E materialization.
__global__ __launch_bounds__(256) void colsum_kernel(
    const unsigned short* __restrict__ qb, const unsigned short* __restrict__ kb,
    float* __restrict__ colsum) {
    const int jt = blockIdx.x, ich = blockIdx.y, b = blockIdx.z;
    const int j0 = jt * 64;
    const int iend = (ich + 1) * 512;
    if (iend <= j0) return;
    const int t = threadIdx.x;
    const int w = t >> 6, lane = t & 63;
    const int m15 = lane & 15, quad = lane >> 4;
    s16x8 bk[4][2];
    for (int ct = 0; ct < 4; ++ct)
        for (int ks = 0; ks < 2; ++ks)
            bk[ct][ks] = *(const s16x8*)(kb +
                (size_t)(b * TT + j0 + ct * 16 + m15) * HD + ks * 32 + quad * 8);
    float csum[4] = {0.f, 0.f, 0.f, 0.f};
    const int istart = max(ich * 512, j0);
    for (int it = istart + w * 16; it < iend; it += 64) {   // 4 waves x 16 rows
        s16x8 aq[2];
        for (int ks = 0; ks < 2; ++ks)
            aq[ks] = *(const s16x8*)(qb +
                (size_t)(b * TT + it + m15) * HD + ks * 32 + quad * 8);
        for (int ct = 0; ct < 4; ++ct) {
            f32x4 s = (f32x4){0.f, 0.f, 0.f, 0.f};
            s = MFMA(aq[0], bk[ct][0], s);
            s = MFMA(aq[1], bk[ct][1], s);
            int gj = j0 + ct * 16 + m15;
            for (int r = 0; r < 4; ++r) {
                int gi = it + quad * 4 + r;
                float e = (gj <= gi) ? __expf(s[r] * SCALE) : 0.f;
                csum[ct] += e;
            }
        }
    }
    for (int ct = 0; ct < 4; ++ct) {
        csum[ct] += __shfl_xor(csum[ct], 16);
        csum[ct] += __shfl_xor(csum[ct], 32);
    }
    if (lane < 16)
        for (int ct = 0; ct < 4; ++ct)
            atomicAdd(&colsum[b * TT + j0 + ct * 16 + lane], csum[ct]);
}

// -------------------------------------------------------------- normpv ----
// ROUND-7 CHANGE: QK^T computed with SWAPPED operands (MFMA(bk, aq)) so the
// S-tile fragments come out transposed: lane (m15,quad) reg r holds
// S[i = i0+w*16+m15][j = j0+ct*16+quad*4+r] — 4 CONSECUTIVE j per lane.
// Store path (the 912 GB/s bottleneck per rocprof: WRITE 149MB @ 12% peak,
// VALU 1.3%) becomes: 1 nontemporal float4 attn store + 1 ds_write_b64 psw
// write per ct (was 16 scalar dword + 16 ds_write_b16). psw layout and the
// PV read side are unchanged. nt keeps the write-once attn stream out of L2.
#define VS 136
#define PS 72
__global__ __launch_bounds__(256, 4) void normpv_kernel(
    const unsigned short* __restrict__ qb, const unsigned short* __restrict__ kb,
    const unsigned short* __restrict__ vb, const float* __restrict__ cs_g,
    float* __restrict__ attn, float* __restrict__ out) {
    const int jch = blockIdx.x;          // j range [jch*512, +512)
    const int ti = blockIdx.y, b = blockIdx.z;
    const int i0 = ti * 64;
    const int jbase = jch * 512;
    float* abase = attn + (size_t)b * TT * TT;
    const int t = threadIdx.x;
    const f32x4 z4 = (f32x4){0.f, 0.f, 0.f, 0.f};
    if (jbase > i0 + 63) {               // fully above diagonal: zeros only
        for (int e = 0; e < 32; ++e) {
            int f4 = e * 256 + t;
            int row = f4 >> 7, c4 = (f4 & 127) * 4;
            __builtin_nontemporal_store(z4,
                (f32x4*)(abase + (size_t)(i0 + row) * TT + jbase + c4));
        }
        return;
    }
    const int w = t >> 6, lane = t & 63;
    const int m15 = lane & 15, quad = lane >> 4;
    __shared__ unsigned short vT[64 * VS];      // vT[h][j-jh], 128-col quarter
    __shared__ unsigned short ps[4 * 16 * PS];  // per-wave P strips (private)
    unsigned short* psw = ps + w * 16 * PS;
    s16x8 aq[2];
    for (int ks = 0; ks < 2; ++ks)
        aq[ks] = *(const s16x8*)(qb +
            (size_t)(b * TT + i0 + w * 16 + m15) * HD + ks * 32 + quad * 8);
    f32x4 o[4];
    for (int ht = 0; ht < 4; ++ht) o[ht] = (f32x4){0.f, 0.f, 0.f, 0.f};
    const float* rcb = cs_g + b * TT;
    const int gi = i0 + w * 16 + m15;    // this lane's attn row (swapped layout)
    float* arow = abase + (size_t)gi * TT;

    for (int qtr = 0; qtr < 4; ++qtr) {
        const int jh = jbase + qtr * 128;
        if (jh > i0 + 63) {              // zero 64x128 region (block-uniform)
            for (int e = 0; e < 8; ++e) {
                int f4 = e * 256 + t;
                int row = f4 >> 5, c4 = (f4 & 31) * 4;
                __builtin_nontemporal_store(z4,
                    (f32x4*)(abase + (size_t)(i0 + row) * TT + jh + c4));
            }
            continue;
        }
        __syncthreads();                 // all waves done reading prior vT
        {   // stage vT: thread owns row jh+(t&127), h-half (t>>7)*32
            const int vrow = t & 127, hseg = (t >> 7) * 32;
            const unsigned short* vp =
                vb + (size_t)(b * TT + jh + vrow) * HD + hseg;
            for (int seg = 0; seg < 4; ++seg) {
                s16x8 vv = *(const s16x8*)(vp + seg * 8);
                for (int qe = 0; qe < 8; ++qe)
                    vT[(hseg + seg * 8 + qe) * VS + vrow] = (unsigned short)vv[qe];
            }
        }
        __syncthreads();                 // vT ready
        for (int jt2 = 0; jt2 < 2; ++jt2) {
            const int j0 = jh + jt2 * 64;
            if (j0 > i0 + 63) {          // zero 64x64 tile (block-uniform)
                for (int e = 0; e < 4; ++e) {
                    int f4 = e * 256 + t;
                    int row = f4 >> 4, c4 = (f4 & 15) * 4;
                    __builtin_nontemporal_store(z4,
                        (f32x4*)(abase + (size_t)(i0 + row) * TT + j0 + c4));
                }
                continue;
            }
            s16x8 bk[4][2];
            for (int ct = 0; ct < 4; ++ct)
                for (int ks = 0; ks < 2; ++ks)
                    bk[ct][ks] = *(const s16x8*)(kb +
                        (size_t)(b * TT + j0 + ct * 16 + m15) * HD + ks * 32 + quad * 8);
            // wave-uniform: is this wave's 16-row strip fully below diagonal?
            const bool fullmask = (j0 + 63 <= i0 + w * 16);
            for (int ct = 0; ct < 4; ++ct) {
                f32x4 s = (f32x4){0.f, 0.f, 0.f, 0.f};
                s = MFMA(bk[ct][0], aq[0], s);     // SWAPPED: S^T fragments
                s = MFMA(bk[ct][1], aq[1], s);
                const int jj = j0 + ct * 16 + quad * 4;
                float4 cs4 = *(const float4*)(rcb + jj);
                f32x4 av;
                if (fullmask) {
                    av[0] = __expf(s[0] * SCALE) * __builtin_amdgcn_rcpf(cs4.x);
                    av[1] = __expf(s[1] * SCALE) * __builtin_amdgcn_rcpf(cs4.y);
                    av[2] = __expf(s[2] * SCALE) * __builtin_amdgcn_rcpf(cs4.z);
                    av[3] = __expf(s[3] * SCALE) * __builtin_amdgcn_rcpf(cs4.w);
                } else {
                    av[0] = (jj + 0 <= gi)
                        ? __expf(s[0] * SCALE) * __builtin_amdgcn_rcpf(cs4.x) : 0.f;
                    av[1] = (jj + 1 <= gi)
                        ? __expf(s[1] * SCALE) * __builtin_amdgcn_rcpf(cs4.y) : 0.f;
                    av[2] = (jj + 2 <= gi)
                        ? __expf(s[2] * SCALE) * __builtin_amdgcn_rcpf(cs4.z) : 0.f;
                    av[3] = (jj + 3 <= gi)
                        ? __expf(s[3] * SCALE) * __builtin_amdgcn_rcpf(cs4.w) : 0.f;
                }
                __builtin_nontemporal_store(av, (f32x4*)(arow + jj));
                s16x4 pk;
                pk[0] = (short)f2bf(av[0]); pk[1] = (short)f2bf(av[1]);
                pk[2] = (short)f2bf(av[2]); pk[3] = (short)f2bf(av[3]);
                *(s16x4*)(psw + m15 * PS + ct * 16 + quad * 4) = pk;
            }
            // PV: psw is wave-private; DS in-order per wave -> no barrier.
            // psw layout (row=i 0..15, col=j-j0 0..63) identical to before.
            for (int ks = 0; ks < 2; ++ks) {
                s16x8 ap = *(const s16x8*)(psw + m15 * PS + ks * 32 + quad * 8);
                for (int ht = 0; ht < 4; ++ht) {
                    s16x8 bv = *(const s16x8*)(vT +
                        (ht * 16 + m15) * VS + jt2 * 64 + ks * 32 + quad * 8);
                    o[ht] = MFMA(ap, bv, o[ht]);
                }
            }
        }
    }
    for (int ht = 0; ht < 4; ++ht)
        for (int r = 0; r < 4; ++r)
            atomicAdd(&out[(size_t)(b * TT + i0 + w * 16 + quad * 4 + r) * HD +
                           ht * 16 + m15], o[ht][r]);
}

// -------------------------------------------------------------- launch ----
extern "C" void kernel_launch(void* const* d_in, const int* in_sizes, int n_in,
                              void* d_out, int out_size, void* d_ws, size_t ws_size,
                              hipStream_t stream) {
    const float* x  = (const float*)d_in[0];
    const float* Wk = (const float*)d_in[1];
    const float* Wq = (const float*)d_in[2];
    const float* Wv = (const float*)d_in[3];
    // d_in[4] = mask sentinel (causal always on) — unused.

    float* out  = (float*)d_out;                       // [B,T,64]
    float* attn = out + (size_t)NB * TT * HD;          // [B,T,T]

    // workspace: k,q,v bf16 (2 MB ea) + colsum fp32 (64 KB)
    unsigned short* kb = (unsigned short*)d_ws;
    unsigned short* qb = kb + (size_t)NB * TT * HD;
    unsigned short* vb = qb + (size_t)NB * TT * HD;
    float* colsum = (float*)(vb + (size_t)NB * TT * HD);

    hipLaunchKernelGGL(qkv_kernel,  dim3(512), dim3(256), 0, stream,
                       x, Wk, Wq, Wv, kb, qb, vb, colsum);
    hipLaunchKernelGGL(colsum_kernel, dim3(32, 4, 8), dim3(256), 0, stream,
                       qb, kb, colsum);
    hipLaunchKernelGGL(normpv_kernel, dim3(4, 32, 8), dim3(256), 0, stream,
                       qb, kb, vb, colsum, attn, out);
}

// Round 9
// 233.855 us; speedup vs baseline: 1.0568x; 1.0568x over previous
//
#include <hip/hip_runtime.h>
#include <hip/hip_bf16.h>

// Problem constants (B=8, T=2048, d_model=512, head_dim=64)
#define TT 2048
#define NB 8
#define DM 512
#define HD 64
static constexpr float SCALE = 0.04419417382415922f; // 512^-0.5

typedef short  s16x8 __attribute__((ext_vector_type(8)));   // 8 bf16 (4 VGPRs)
typedef short  s16x4 __attribute__((ext_vector_type(4)));   // 4 bf16 (2 VGPRs)
typedef float  f32x4 __attribute__((ext_vector_type(4)));

#define MFMA(a, b, c) __builtin_amdgcn_mfma_f32_16x16x32_bf16((a), (b), (c), 0, 0, 0)

// fp32 -> bf16 (RNE)
static __device__ inline unsigned short f2bf(float f) {
    unsigned int u = __float_as_uint(f);
    u += 0x7FFFu + ((u >> 16) & 1u);
    return (unsigned short)(u >> 16);
}

// ---------------------------------------------------------------- prep ----
// Best-measured (r2): zero out + zero colsum + convert W->bf16 ONCE.
// (r6/r7 folded W-conversion into qkv's hot loop -> 512x redundant f2bf,
//  a real regression; reverted.)
__global__ __launch_bounds__(256) void prep_kernel(
    const float* __restrict__ Wk, const float* __restrict__ Wq,
    const float* __restrict__ Wv, unsigned short* __restrict__ wbf,
    float* __restrict__ colsum, float* __restrict__ out) {
    const int bi = blockIdx.x, t = threadIdx.x;
    const float4 z4 = make_float4(0.f, 0.f, 0.f, 0.f);
    if (bi < 1024) {                     // out: 1,048,576 floats = 262,144 f4
        int i = (bi * 256 + t) * 4;
        *(float4*)(out + i) = z4;
    } else if (bi < 1040) {              // colsum: 16,384 floats = 4,096 f4
        int i = ((bi - 1024) * 256 + t) * 4;
        *(float4*)(colsum + i) = z4;
    } else {                             // convert W: 3*64*512 = 98,304 elems
        int g = ((bi - 1040) * 256 + t) * 4;
        int mat = g >> 15, off = g & 32767;
        const float* src = (mat == 0) ? Wk : (mat == 1) ? Wq : Wv;
        float4 f = *(const float4*)(src + off);
        wbf[g + 0] = f2bf(f.x); wbf[g + 1] = f2bf(f.y);
        wbf[g + 2] = f2bf(f.z); wbf[g + 3] = f2bf(f.w);
    }
}

// ----------------------------------------------------------------- qkv ----
// Best-measured (r2): M=32 rows/block, N=192, K=512, grid 512. x staged via
// LDS (fp32->bf16); W read from pre-converted bf16 (wbf).
#define XS 72
__global__ __launch_bounds__(256) void qkv_kernel(
    const float* __restrict__ x, const unsigned short* __restrict__ wbf,
    unsigned short* __restrict__ kb, unsigned short* __restrict__ qb,
    unsigned short* __restrict__ vb) {
    __shared__ unsigned short xs[32 * XS];
    const int i0 = blockIdx.x * 32;
    const int t = threadIdx.x;
    const int w = t >> 6, lane = t & 63;
    const int m15 = lane & 15, quad = lane >> 4;
    const int srow = t >> 3, c8 = (t & 7) * 8;    // staging: 32 rows x 64 cols
    f32x4 acc[2][3];
    for (int mt = 0; mt < 2; ++mt)
        for (int ct = 0; ct < 3; ++ct)
            acc[mt][ct] = (f32x4){0.f, 0.f, 0.f, 0.f};

    for (int kc = 0; kc < DM; kc += 64) {
        __syncthreads();
        {
            const float* gp = x + (size_t)(i0 + srow) * DM + kc + c8;
            float4 f0 = *(const float4*)gp;
            float4 f1 = *(const float4*)(gp + 4);
            s16x8 h;
            h[0] = (short)f2bf(f0.x); h[1] = (short)f2bf(f0.y);
            h[2] = (short)f2bf(f0.z); h[3] = (short)f2bf(f0.w);
            h[4] = (short)f2bf(f1.x); h[5] = (short)f2bf(f1.y);
            h[6] = (short)f2bf(f1.z); h[7] = (short)f2bf(f1.w);
            *(s16x8*)(xs + srow * XS + c8) = h;
        }
        __syncthreads();
        for (int ks = 0; ks < 2; ++ks) {
            s16x8 a[2];
            for (int mt = 0; mt < 2; ++mt)
                a[mt] = *(const s16x8*)(xs + (mt * 16 + m15) * XS + ks * 32 + quad * 8);
            for (int ct = 0; ct < 3; ++ct) {
                s16x8 bfr = *(const s16x8*)(wbf +
                    (size_t)((w * 3 + ct) * 16 + m15) * DM + kc + ks * 32 + quad * 8);
                acc[0][ct] = MFMA(a[0], bfr, acc[0][ct]);
                acc[1][ct] = MFMA(a[1], bfr, acc[1][ct]);
            }
        }
    }
    for (int mt = 0; mt < 2; ++mt)
        for (int ct = 0; ct < 3; ++ct) {
            int tile16 = w * 3 + ct;
            unsigned short* outp = (tile16 < 4) ? kb : (tile16 < 8) ? qb : vb;
            int col = (tile16 & 3) * 16 + m15;
            for (int r = 0; r < 4; ++r) {
                int grow = i0 + mt * 16 + quad * 4 + r;
                outp[(size_t)grow * HD + col] = f2bf(acc[mt][ct][r]);
            }
        }
}

// -------------------------------------------------------------- colsum ----
// colsum[b][j] = sum_{i>=j} exp(SCALE * q_i . k_j)  — no E materialization.
__global__ __launch_bounds__(256) void colsum_kernel(
    const unsigned short* __restrict__ qb, const unsigned short* __restrict__ kb,
    float* __restrict__ colsum) {
    const int jt = blockIdx.x, ich = blockIdx.y, b = blockIdx.z;
    const int j0 = jt * 64;
    const int iend = (ich + 1) * 512;
    if (iend <= j0) return;
    const int t = threadIdx.x;
    const int w = t >> 6, lane = t & 63;
    const int m15 = lane & 15, quad = lane >> 4;
    s16x8 bk[4][2];
    for (int ct = 0; ct < 4; ++ct)
        for (int ks = 0; ks < 2; ++ks)
            bk[ct][ks] = *(const s16x8*)(kb +
                (size_t)(b * TT + j0 + ct * 16 + m15) * HD + ks * 32 + quad * 8);
    float csum[4] = {0.f, 0.f, 0.f, 0.f};
    const int istart = max(ich * 512, j0);
    for (int it = istart + w * 16; it < iend; it += 64) {   // 4 waves x 16 rows
        s16x8 aq[2];
        for (int ks = 0; ks < 2; ++ks)
            aq[ks] = *(const s16x8*)(qb +
                (size_t)(b * TT + it + m15) * HD + ks * 32 + quad * 8);
        for (int ct = 0; ct < 4; ++ct) {
            f32x4 s = (f32x4){0.f, 0.f, 0.f, 0.f};
            s = MFMA(aq[0], bk[ct][0], s);
            s = MFMA(aq[1], bk[ct][1], s);
            int gj = j0 + ct * 16 + m15;
            for (int r = 0; r < 4; ++r) {
                int gi = it + quad * 4 + r;
                float e = (gj <= gi) ? __expf(s[r] * SCALE) : 0.f;
                csum[ct] += e;
            }
        }
    }
    for (int ct = 0; ct < 4; ++ct) {
        csum[ct] += __shfl_xor(csum[ct], 16);
        csum[ct] += __shfl_xor(csum[ct], 32);
    }
    if (lane < 16)
        for (int ct = 0; ct < 4; ++ct)
            atomicAdd(&colsum[b * TT + j0 + ct * 16 + lane], csum[ct]);
}

// -------------------------------------------------------------- normpv ----
// Best-measured (r7, profiler-verified: dispatch 163us -> <85us): QK^T with
// SWAPPED operands (MFMA(bk, aq)) so lane (m15,quad) reg r holds
// S[i = i0+w*16+m15][j = j0+ct*16+quad*4+r] — 4 CONSECUTIVE j per lane.
// Store path: 1 nontemporal float4 attn store + 1 ds_write_b64 psw write per
// ct (was 16 scalar dword + 16 ds_write_b16). psw layout & PV side unchanged.
#define VS 136
#define PS 72
__global__ __launch_bounds__(256, 4) void normpv_kernel(
    const unsigned short* __restrict__ qb, const unsigned short* __restrict__ kb,
    const unsigned short* __restrict__ vb, const float* __restrict__ cs_g,
    float* __restrict__ attn, float* __restrict__ out) {
    const int jch = blockIdx.x;          // j range [jch*512, +512)
    const int ti = blockIdx.y, b = blockIdx.z;
    const int i0 = ti * 64;
    const int jbase = jch * 512;
    float* abase = attn + (size_t)b * TT * TT;
    const int t = threadIdx.x;
    const f32x4 z4 = (f32x4){0.f, 0.f, 0.f, 0.f};
    if (jbase > i0 + 63) {               // fully above diagonal: zeros only
        for (int e = 0; e < 32; ++e) {
            int f4 = e * 256 + t;
            int row = f4 >> 7, c4 = (f4 & 127) * 4;
            __builtin_nontemporal_store(z4,
                (f32x4*)(abase + (size_t)(i0 + row) * TT + jbase + c4));
        }
        return;
    }
    const int w = t >> 6, lane = t & 63;
    const int m15 = lane & 15, quad = lane >> 4;
    __shared__ unsigned short vT[64 * VS];      // vT[h][j-jh], 128-col quarter
    __shared__ unsigned short ps[4 * 16 * PS];  // per-wave P strips (private)
    unsigned short* psw = ps + w * 16 * PS;
    s16x8 aq[2];
    for (int ks = 0; ks < 2; ++ks)
        aq[ks] = *(const s16x8*)(qb +
            (size_t)(b * TT + i0 + w * 16 + m15) * HD + ks * 32 + quad * 8);
    f32x4 o[4];
    for (int ht = 0; ht < 4; ++ht) o[ht] = (f32x4){0.f, 0.f, 0.f, 0.f};
    const float* rcb = cs_g + b * TT;
    const int gi = i0 + w * 16 + m15;    // this lane's attn row (swapped layout)
    float* arow = abase + (size_t)gi * TT;

    for (int qtr = 0; qtr < 4; ++qtr) {
        const int jh = jbase + qtr * 128;
        if (jh > i0 + 63) {              // zero 64x128 region (block-uniform)
            for (int e = 0; e < 8; ++e) {
                int f4 = e * 256 + t;
                int row = f4 >> 5, c4 = (f4 & 31) * 4;
                __builtin_nontemporal_store(z4,
                    (f32x4*)(abase + (size_t)(i0 + row) * TT + jh + c4));
            }
            continue;
        }
        __syncthreads();                 // all waves done reading prior vT
        {   // stage vT: thread owns row jh+(t&127), h-half (t>>7)*32
            const int vrow = t & 127, hseg = (t >> 7) * 32;
            const unsigned short* vp =
                vb + (size_t)(b * TT + jh + vrow) * HD + hseg;
            for (int seg = 0; seg < 4; ++seg) {
                s16x8 vv = *(const s16x8*)(vp + seg * 8);
                for (int qe = 0; qe < 8; ++qe)
                    vT[(hseg + seg * 8 + qe) * VS + vrow] = (unsigned short)vv[qe];
            }
        }
        __syncthreads();                 // vT ready
        for (int jt2 = 0; jt2 < 2; ++jt2) {
            const int j0 = jh + jt2 * 64;
            if (j0 > i0 + 63) {          // zero 64x64 tile (block-uniform)
                for (int e = 0; e < 4; ++e) {
                    int f4 = e * 256 + t;
                    int row = f4 >> 4, c4 = (f4 & 15) * 4;
                    __builtin_nontemporal_store(z4,
                        (f32x4*)(abase + (size_t)(i0 + row) * TT + j0 + c4));
                }
                continue;
            }
            s16x8 bk[4][2];
            for (int ct = 0; ct < 4; ++ct)
                for (int ks = 0; ks < 2; ++ks)
                    bk[ct][ks] = *(const s16x8*)(kb +
                        (size_t)(b * TT + j0 + ct * 16 + m15) * HD + ks * 32 + quad * 8);
            // wave-uniform: is this wave's 16-row strip fully below diagonal?
            const bool fullmask = (j0 + 63 <= i0 + w * 16);
            for (int ct = 0; ct < 4; ++ct) {
                f32x4 s = (f32x4){0.f, 0.f, 0.f, 0.f};
                s = MFMA(bk[ct][0], aq[0], s);     // SWAPPED: S^T fragments
                s = MFMA(bk[ct][1], aq[1], s);
                const int jj = j0 + ct * 16 + quad * 4;
                float4 cs4 = *(const float4*)(rcb + jj);
                f32x4 av;
                if (fullmask) {
                    av[0] = __expf(s[0] * SCALE) * __builtin_amdgcn_rcpf(cs4.x);
                    av[1] = __expf(s[1] * SCALE) * __builtin_amdgcn_rcpf(cs4.y);
                    av[2] = __expf(s[2] * SCALE) * __builtin_amdgcn_rcpf(cs4.z);
                    av[3] = __expf(s[3] * SCALE) * __builtin_amdgcn_rcpf(cs4.w);
                } else {
                    av[0] = (jj + 0 <= gi)
                        ? __expf(s[0] * SCALE) * __builtin_amdgcn_rcpf(cs4.x) : 0.f;
                    av[1] = (jj + 1 <= gi)
                        ? __expf(s[1] * SCALE) * __builtin_amdgcn_rcpf(cs4.y) : 0.f;
                    av[2] = (jj + 2 <= gi)
                        ? __expf(s[2] * SCALE) * __builtin_amdgcn_rcpf(cs4.z) : 0.f;
                    av[3] = (jj + 3 <= gi)
                        ? __expf(s[3] * SCALE) * __builtin_amdgcn_rcpf(cs4.w) : 0.f;
                }
                __builtin_nontemporal_store(av, (f32x4*)(arow + jj));
                s16x4 pk;
                pk[0] = (short)f2bf(av[0]); pk[1] = (short)f2bf(av[1]);
                pk[2] = (short)f2bf(av[2]); pk[3] = (short)f2bf(av[3]);
                *(s16x4*)(psw + m15 * PS + ct * 16 + quad * 4) = pk;
            }
            // PV: psw is wave-private; DS in-order per wave -> no barrier.
            // psw layout (row=i 0..15, col=j-j0 0..63) identical to before.
            for (int ks = 0; ks < 2; ++ks) {
                s16x8 ap = *(const s16x8*)(psw + m15 * PS + ks * 32 + quad * 8);
                for (int ht = 0; ht < 4; ++ht) {
                    s16x8 bv = *(const s16x8*)(vT +
                        (ht * 16 + m15) * VS + jt2 * 64 + ks * 32 + quad * 8);
                    o[ht] = MFMA(ap, bv, o[ht]);
                }
            }
        }
    }
    for (int ht = 0; ht < 4; ++ht)
        for (int r = 0; r < 4; ++r)
            atomicAdd(&out[(size_t)(b * TT + i0 + w * 16 + quad * 4 + r) * HD +
                           ht * 16 + m15], o[ht][r]);
}

// -------------------------------------------------------------- launch ----
extern "C" void kernel_launch(void* const* d_in, const int* in_sizes, int n_in,
                              void* d_out, int out_size, void* d_ws, size_t ws_size,
                              hipStream_t stream) {
    const float* x  = (const float*)d_in[0];
    const float* Wk = (const float*)d_in[1];
    const float* Wq = (const float*)d_in[2];
    const float* Wv = (const float*)d_in[3];
    // d_in[4] = mask sentinel (causal always on) — unused.

    float* out  = (float*)d_out;                       // [B,T,64]
    float* attn = out + (size_t)NB * TT * HD;          // [B,T,T]

    // workspace: k,q,v bf16 (2 MB ea) + colsum fp32 (64 KB) + wbf bf16 (196 KB)
    unsigned short* kb = (unsigned short*)d_ws;
    unsigned short* qb = kb + (size_t)NB * TT * HD;
    unsigned short* vb = qb + (size_t)NB * TT * HD;
    float* colsum = (float*)(vb + (size_t)NB * TT * HD);
    unsigned short* wbf = (unsigned short*)(colsum + NB * TT);

    hipLaunchKernelGGL(prep_kernel, dim3(1136), dim3(256), 0, stream,
                       Wk, Wq, Wv, wbf, colsum, out);
    hipLaunchKernelGGL(qkv_kernel,  dim3(512), dim3(256), 0, stream,
                       x, wbf, kb, qb, vb);
    hipLaunchKernelGGL(colsum_kernel, dim3(32, 4, 8), dim3(256), 0, stream,
                       qb, kb, colsum);
    hipLaunchKernelGGL(normpv_kernel, dim3(4, 32, 8), dim3(256), 0, stream,
                       qb, kb, vb, colsum, attn, out);
}